// Round 8
// baseline (7652.988 us; speedup 1.0000x reference)
//
#include <hip/hip_runtime.h>
#include <hip/hip_bf16.h>
#include <math.h>

#define T_STEPS 512
#define BATCH   64
#define IN_DIM  1024
#define HID     1024
#define BH_SZ   (BATCH * HID)

typedef short bf16x8 __attribute__((ext_vector_type(8)));
typedef float f32x4  __attribute__((ext_vector_type(4)));
typedef unsigned u32x4 __attribute__((ext_vector_type(4)));
typedef unsigned long long u64;

// ---- coherent (agent-scope, cache-bypassing) accessors --------------------
__device__ __forceinline__ u64 ld_coh_u64(const u64* p) {
    return __hip_atomic_load(p, __ATOMIC_RELAXED, __HIP_MEMORY_SCOPE_AGENT);
}
__device__ __forceinline__ void st_coh_u64(u64* p, u64 v) {
    __hip_atomic_store(p, v, __ATOMIC_RELAXED, __HIP_MEMORY_SCOPE_AGENT);
}

// ---- bf16 split helpers (RNE) ---------------------------------------------
__device__ __forceinline__ unsigned short f2bf(float x) {
    unsigned u = __builtin_bit_cast(unsigned, x);
    unsigned r = u + 0x7FFFu + ((u >> 16) & 1u);
    return (unsigned short)(r >> 16);
}
__device__ __forceinline__ float bf2f(unsigned short h) {
    unsigned u = ((unsigned)h) << 16;
    return __builtin_bit_cast(float, u);
}
__device__ __forceinline__ float fast_tanh(float x) {
    float e = __expf(2.0f * x);
    return 1.0f - 2.0f * __builtin_amdgcn_rcpf(e + 1.0f);
}

// ---------------------------------------------------------------------------
// Kernel A: xp = input @ W_ih^T + b_ih + b_hh   (unchanged)
// ---------------------------------------------------------------------------
__global__ __launch_bounds__(256) void xproj_kernel(
    const float* __restrict__ A,
    const float* __restrict__ W,
    const float* __restrict__ b_ih,
    const float* __restrict__ b_hh,
    float* __restrict__ out)
{
    constexpr int BM = 128, BN = 64, BK = 32;
    __shared__ float As[BK][BM + 4];
    __shared__ float Bs[BK][BN + 4];

    const int n0 = blockIdx.x * BN;
    const int m0 = blockIdx.y * BM;
    const int tid = threadIdx.x;
    const int tx = tid & 15;
    const int ty = tid >> 4;

    float acc[8][4] = {};

    for (int k0 = 0; k0 < IN_DIM; k0 += BK) {
        #pragma unroll
        for (int i = 0; i < 4; i++) {
            int f4 = i * 256 + tid;
            int r = f4 >> 3, c4 = f4 & 7;
            float4 v = *(const float4*)(A + (long)(m0 + r) * IN_DIM + k0 + c4 * 4);
            As[c4 * 4 + 0][r] = v.x;
            As[c4 * 4 + 1][r] = v.y;
            As[c4 * 4 + 2][r] = v.z;
            As[c4 * 4 + 3][r] = v.w;
        }
        #pragma unroll
        for (int i = 0; i < 2; i++) {
            int f4 = i * 256 + tid;
            int r = f4 >> 3, c4 = f4 & 7;
            float4 v = *(const float4*)(W + (long)(n0 + r) * IN_DIM + k0 + c4 * 4);
            Bs[c4 * 4 + 0][r] = v.x;
            Bs[c4 * 4 + 1][r] = v.y;
            Bs[c4 * 4 + 2][r] = v.z;
            Bs[c4 * 4 + 3][r] = v.w;
        }
        __syncthreads();

        #pragma unroll 8
        for (int k = 0; k < BK; k++) {
            float4 a0 = *(const float4*)&As[k][ty * 8];
            float4 a1 = *(const float4*)&As[k][ty * 8 + 4];
            float4 bv = *(const float4*)&Bs[k][tx * 4];
            float av[8] = {a0.x, a0.y, a0.z, a0.w, a1.x, a1.y, a1.z, a1.w};
            float bb[4] = {bv.x, bv.y, bv.z, bv.w};
            #pragma unroll
            for (int i = 0; i < 8; i++)
                #pragma unroll
                for (int j = 0; j < 4; j++)
                    acc[i][j] += av[i] * bb[j];
        }
        __syncthreads();
    }

    float4 bi = *(const float4*)&b_ih[n0 + tx * 4];
    float4 bh = *(const float4*)&b_hh[n0 + tx * 4];
    float bsum[4] = {bi.x + bh.x, bi.y + bh.y, bi.z + bh.z, bi.w + bh.w};

    #pragma unroll
    for (int i = 0; i < 8; i++) {
        float4 o;
        o.x = acc[i][0] + bsum[0];
        o.y = acc[i][1] + bsum[1];
        o.z = acc[i][2] + bsum[2];
        o.w = acc[i][3] + bsum[3];
        *(float4*)(out + (long)(m0 + ty * 8 + i) * HID + n0 + tx * 4) = o;
    }
}

// ---------------------------------------------------------------------------
// Kernel B v8: MFMA dot + TAGGED-DATA h exchange (no flags, no grid barrier).
// Each h element: u64 = (tag = t+1)<<32 | (bf16hi | bf16lo<<16).
// Producer: single fire-and-forget coherent u64 store per element.
// Consumer: batched 32x coherent u64 loads, retry until all tags == t.
// Overwrite safety: a block cannot reach its step-(t+2) store without
// validating ALL tags t+1, which requires every peer to have completed
// step t+1, which requires their reads of h_t done. 2 syncthreads/step.
// hcomm MUST be zeroed per launch (stale tags from a previous graph
// replay would alias) -> in-graph hipMemsetAsync below.
// ---------------------------------------------------------------------------
__global__ __launch_bounds__(512) void rnn_kernel(
    const float* __restrict__ h0,
    const float* __restrict__ Whh,
    float* __restrict__ out,         // [T][B][H] xp in -> h out; h_last at end
    u64* hcomm)                      // [2][B][H] tagged packed h exchange
{
    __shared__ unsigned short Whi[16 * 1024];
    __shared__ unsigned short Wlo[16 * 1024];
    __shared__ unsigned short Hhi[16 * 1024];
    __shared__ unsigned short Hlo[16 * 1024];
    __shared__ f32x4 Pred[8][64];

    const int bid = blockIdx.x;
    const int j0 = (bid & 63) * 16;
    const int b0 = (bid >> 6) * 16;
    const int tid  = threadIdx.x;
    const int lane = tid & 63;
    const int w    = tid >> 6;        // wave 0..7 -> k-range [w*128,(w+1)*128)

    // ---- stage W_hh rows j0..j0+15 as bf16 hi/lo, XOR-swizzled ----
    #pragma unroll
    for (int i = 0; i < 4; i++) {
        int c = i * 512 + tid;            // chunk of 8 elems
        int row = c >> 7;
        int k0 = (c & 127) * 8;
        const float* src = Whh + (size_t)(j0 + row) * HID + k0;
        float4 v0 = *(const float4*)(src);
        float4 v1 = *(const float4*)(src + 4);
        float vv[8] = {v0.x, v0.y, v0.z, v0.w, v1.x, v1.y, v1.z, v1.w};
        bf16x8 hi8, lo8;
        #pragma unroll
        for (int e = 0; e < 8; e++) {
            unsigned short h = f2bf(vv[e]);
            hi8[e] = (short)h;
            lo8[e] = (short)f2bf(vv[e] - bf2f(h));
        }
        int ofs = row * 1024 + (k0 ^ ((row & 7) << 3));
        *(bf16x8*)&Whi[ofs] = hi8;
        *(bf16x8*)&Wlo[ofs] = lo8;
    }

    const int o = tid;                 // tid<256: b = o>>4, j = o&15
    const size_t out_off = (size_t)(b0 + (o >> 4)) * HID + (size_t)(j0 + (o & 15));
    float xp_cur = (tid < 256) ? out[out_off] : 0.f;

    // fragment addressing: lane reads row (lane&15), 8 bf16 at k-base
    const int frow = lane & 15;
    const int ksub = (lane >> 4) * 8;          // 0,8,16,24
    const int sw   = (frow & 7) << 3;

    for (int t = 0; t < T_STEPS; t++) {
        // ---- stage h_{t-1} (16 rows) into Hhi/Hlo ----
        if (t == 0) {
            #pragma unroll
            for (int i = 0; i < 4; i++) {
                int c = i * 512 + tid;
                int row = c >> 7;
                int k0 = (c & 127) * 8;
                const float* p = h0 + (size_t)(b0 + row) * HID + k0;
                float4 v0 = *(const float4*)(p);
                float4 v1 = *(const float4*)(p + 4);
                float vv[8] = {v0.x, v0.y, v0.z, v0.w, v1.x, v1.y, v1.z, v1.w};
                bf16x8 hi8, lo8;
                #pragma unroll
                for (int e = 0; e < 8; e++) {
                    unsigned short h = f2bf(vv[e]);
                    hi8[e] = (short)h;
                    lo8[e] = (short)f2bf(vv[e] - bf2f(h));
                }
                int ofs = row * 1024 + (k0 ^ ((row & 7) << 3));
                *(bf16x8*)&Hhi[ofs] = hi8;
                *(bf16x8*)&Hlo[ofs] = lo8;
            }
        } else {
            const u64* hsrc = hcomm + (size_t)((t + 1) & 1) * BH_SZ;
            const unsigned expect = (unsigned)t;   // tag stored by step t-1
            u64 pv[32];
            // batched load + tag-validate; retry whole batch on miss
            for (;;) {
                #pragma unroll
                for (int i = 0; i < 4; i++) {
                    int c = i * 512 + tid;
                    int row = c >> 7;
                    int k0 = (c & 127) * 8;
                    const u64* p = hsrc + (size_t)(b0 + row) * HID + k0;
                    #pragma unroll
                    for (int e = 0; e < 8; e++)
                        pv[i * 8 + e] = ld_coh_u64(p + e);
                }
                unsigned ok = 1u;
                #pragma unroll
                for (int e = 0; e < 32; e++)
                    ok &= ((unsigned)(pv[e] >> 32) == expect) ? 1u : 0u;
                if (ok) break;
                __builtin_amdgcn_s_sleep(1);
            }
            // unpack + LDS write
            #pragma unroll
            for (int i = 0; i < 4; i++) {
                int c = i * 512 + tid;
                int row = c >> 7;
                int k0 = (c & 127) * 8;
                u32x4 hiu, lou;
                #pragma unroll
                for (int e = 0; e < 4; e++) {
                    unsigned p0 = (unsigned)pv[i * 8 + 2 * e];      // hi|lo<<16
                    unsigned p1 = (unsigned)pv[i * 8 + 2 * e + 1];
                    hiu[e] = (p0 & 0xFFFFu) | (p1 << 16);
                    lou[e] = (p0 >> 16) | (p1 & 0xFFFF0000u);
                }
                int ofs = row * 1024 + (k0 ^ ((row & 7) << 3));
                *(u32x4*)&Hhi[ofs] = hiu;
                *(u32x4*)&Hlo[ofs] = lou;
            }
        }
        __syncthreads();   // sync A: H staged; also orders prev reduce-reads
                           // of Pred before this step's Pred writes

        // ---- MFMA dot: wave w covers k in [w*128,(w+1)*128) ----
        {
            f32x4 acc = {0.f, 0.f, 0.f, 0.f};
            #pragma unroll
            for (int kk = 0; kk < 4; kk++) {
                int kidx = w * 128 + kk * 32 + ksub;       // full k index
                int ofs  = frow * 1024 + (kidx ^ sw);      // XOR after add
                bf16x8 ahi = *(const bf16x8*)&Hhi[ofs];
                bf16x8 alo = *(const bf16x8*)&Hlo[ofs];
                bf16x8 bhi = *(const bf16x8*)&Whi[ofs];
                bf16x8 blo = *(const bf16x8*)&Wlo[ofs];
                acc = __builtin_amdgcn_mfma_f32_16x16x32_bf16(ahi, bhi, acc, 0, 0, 0);
                acc = __builtin_amdgcn_mfma_f32_16x16x32_bf16(ahi, blo, acc, 0, 0, 0);
                acc = __builtin_amdgcn_mfma_f32_16x16x32_bf16(alo, bhi, acc, 0, 0, 0);
            }
            Pred[w][lane] = acc;   // D: col=lane&15 (j), rows (lane>>4)*4+r (b)
        }
        __syncthreads();   // sync B: Pred ready; all H reads done

        // ---- reduce + tanh + tagged fire-and-forget store ----
        if (tid < 256) {
            const int b = o >> 4, j = o & 15;
            const int plane = ((b >> 2) << 4) | j;   // source lane in each wave
            const int pr = b & 3;                    // source reg
            float s = xp_cur;
            #pragma unroll
            for (int k = 0; k < 8; k++) s += Pred[k][plane][pr];
            float hn = fast_tanh(s);
            unsigned short hi = f2bf(hn);
            unsigned short lo = f2bf(hn - bf2f(hi));
            u64 word = ((u64)(unsigned)(t + 1) << 32)
                     | (u64)((unsigned)hi | ((unsigned)lo << 16));
            st_coh_u64(hcomm + (size_t)(t & 1) * BH_SZ + out_off, word);
            // off-critical-path cached stores / next-xp prefetch
            out[(size_t)t * BH_SZ + out_off] = hn;
            if (t == T_STEPS - 1)
                out[(size_t)T_STEPS * BH_SZ + out_off] = hn;
            if (t + 1 < T_STEPS)
                xp_cur = out[(size_t)(t + 1) * BH_SZ + out_off];
        }
        // no sync here: next stage's tag-retry tolerates in-flight stores
    }
}

// ---------------------------------------------------------------------------
extern "C" void kernel_launch(void* const* d_in, const int* in_sizes, int n_in,
                              void* d_out, int out_size, void* d_ws, size_t ws_size,
                              hipStream_t stream)
{
    const float* input  = (const float*)d_in[0];
    const float* hidden = (const float*)d_in[1];
    const float* W_ih   = (const float*)d_in[2];
    const float* W_hh   = (const float*)d_in[3];
    const float* b_ih   = (const float*)d_in[4];
    const float* b_hh   = (const float*)d_in[5];
    float* out = (float*)d_out;

    u64* hcomm = (u64*)d_ws;   // [2][B][H] u64 = 1 MB
    // zero tags every launch (also every graph replay) — stale tags from a
    // previous replay would exactly alias this run's expected tags
    hipMemsetAsync(hcomm, 0, (size_t)2 * BH_SZ * sizeof(u64), stream);

    dim3 gridA(HID / 64, (T_STEPS * BATCH) / 128, 1);
    xproj_kernel<<<gridA, 256, 0, stream>>>(input, W_ih, b_ih, b_hh, out);

    rnn_kernel<<<256, 512, 0, stream>>>(hidden, W_hh, out, hcomm);
}

// Round 9
// 2833.769 us; speedup vs baseline: 2.7006x; 2.7006x over previous
//
#include <hip/hip_runtime.h>
#include <hip/hip_bf16.h>
#include <math.h>

#define T_STEPS 512
#define BATCH   64
#define IN_DIM  1024
#define HID     1024
#define BH_SZ   (BATCH * HID)

typedef short bf16x8 __attribute__((ext_vector_type(8)));
typedef float f32x4  __attribute__((ext_vector_type(4)));
typedef unsigned u32x4 __attribute__((ext_vector_type(4)));
typedef unsigned u32x2 __attribute__((ext_vector_type(2)));
typedef unsigned long long u64;

// ---- coherent (agent-scope, cache-bypassing) accessors --------------------
__device__ __forceinline__ unsigned ld_coh_u32(const unsigned* p) {
    return __hip_atomic_load(p, __ATOMIC_RELAXED, __HIP_MEMORY_SCOPE_AGENT);
}
__device__ __forceinline__ void st_coh_u32(unsigned* p, unsigned v) {
    __hip_atomic_store(p, v, __ATOMIC_RELAXED, __HIP_MEMORY_SCOPE_AGENT);
}
__device__ __forceinline__ u64 ld_coh_u64(const u64* p) {
    return __hip_atomic_load(p, __ATOMIC_RELAXED, __HIP_MEMORY_SCOPE_AGENT);
}

// ---- bf16 split helpers (RNE) ---------------------------------------------
__device__ __forceinline__ unsigned short f2bf(float x) {
    unsigned u = __builtin_bit_cast(unsigned, x);
    unsigned r = u + 0x7FFFu + ((u >> 16) & 1u);
    return (unsigned short)(r >> 16);
}
__device__ __forceinline__ float bf2f(unsigned short h) {
    unsigned u = ((unsigned)h) << 16;
    return __builtin_bit_cast(float, u);
}
__device__ __forceinline__ float fast_tanh(float x) {
    float e = __expf(2.0f * x);
    return 1.0f - 2.0f * __builtin_amdgcn_rcpf(e + 1.0f);
}

// ---------------------------------------------------------------------------
// pack: f32 -> u32 (bf16hi | bf16lo<<16), vectorized float4, grid-stride
// ---------------------------------------------------------------------------
__global__ __launch_bounds__(256) void pack_bf16_kernel(
    const float* __restrict__ src, unsigned* __restrict__ dst, int n4)
{
    int idx = blockIdx.x * 256 + threadIdx.x;
    int stride = gridDim.x * 256;
    for (int i = idx; i < n4; i += stride) {
        float4 v = *(const float4*)(src + (size_t)i * 4);
        float vv[4] = {v.x, v.y, v.z, v.w};
        u32x4 o;
        #pragma unroll
        for (int e = 0; e < 4; e++) {
            unsigned short h = f2bf(vv[e]);
            unsigned short l = f2bf(vv[e] - bf2f(h));
            o[e] = (unsigned)h | ((unsigned)l << 16);
        }
        *(u32x4*)(dst + (size_t)i * 4) = o;
    }
}

// ---------------------------------------------------------------------------
// xproj MFMA: C[m][n] = sum_k x[m][k]*W[n][k] + bias, 3-term bf16 split.
// IN-PLACE: xpk (u32 packed x) occupies the same buffer the f32 result is
// written to. Per block: reads rows m0..m0+63 (all k) across the k-loop,
// writes the same rows (all n) only in the epilogue -> no hazard; rows are
// block-private. BM=64, BN=1024 (full), BK=32. 512 thr = 8 waves, wave
// covers n in [w*128,(w+1)*128): acc[4 m][8 n] f32x4 = 128 VGPR.
// ---------------------------------------------------------------------------
__global__ __launch_bounds__(512, 2) void xproj_mfma_kernel(
    unsigned* __restrict__ xpk,       // [32768][1024] u32 in -> f32 out
    const unsigned* __restrict__ Wpk, // [1024][1024] u32
    const float* __restrict__ b_ih,
    const float* __restrict__ b_hh)
{
    __shared__ unsigned short Ahi[64 * 32];
    __shared__ unsigned short Alo[64 * 32];
    __shared__ unsigned short Bhi[1024 * 32];
    __shared__ unsigned short Blo[1024 * 32];

    const int m0 = blockIdx.x * 64;
    const int tid  = threadIdx.x;
    const int lane = tid & 63;
    const int w    = tid >> 6;            // n-range [w*128, w*128+128)

    f32x4 acc[4][8] = {};

    const int frow = lane & 15;
    const int kf   = (lane >> 4) * 8;     // 0,8,16,24

    for (int k0 = 0; k0 < IN_DIM; k0 += 32) {
        // ---- stage A: 64 rows x 32 k (u32 -> hi/lo bf16) ----
        #pragma unroll
        for (int i = 0; i < 2; i++) {
            int c2 = i * 512 + tid;           // [0,1024): pairs of u32
            int row = c2 >> 4;                // 16 pairs (32 u32) per row
            int kc = (c2 & 15) * 2;
            const unsigned* p = xpk + (size_t)(m0 + row) * IN_DIM + k0 + kc;
            unsigned w0 = p[0], w1 = p[1];
            int ofs = row * 32 + (kc ^ ((row & 3) << 3));
            *(unsigned*)&Ahi[ofs] = (w0 & 0xFFFFu) | (w1 << 16);
            *(unsigned*)&Alo[ofs] = (w0 >> 16) | (w1 & 0xFFFF0000u);
        }
        // ---- stage B: 1024 rows x 32 k ----
        #pragma unroll
        for (int i = 0; i < 16; i++) {
            int c4 = i * 512 + tid;           // [0,8192): quads of u32
            int row = c4 >> 3;                // 8 quads (32 u32) per row
            int kq = (c4 & 7) * 4;
            u32x4 q = *(const u32x4*)(Wpk + (size_t)row * IN_DIM + k0 + kq);
            int ofs = row * 32 + (kq ^ ((row & 3) << 3));
            u32x2 h2, l2;
            h2[0] = (q[0] & 0xFFFFu) | (q[1] << 16);
            h2[1] = (q[2] & 0xFFFFu) | (q[3] << 16);
            l2[0] = (q[0] >> 16) | (q[1] & 0xFFFF0000u);
            l2[1] = (q[2] >> 16) | (q[3] & 0xFFFF0000u);
            *(u32x2*)&Bhi[ofs] = h2;
            *(u32x2*)&Blo[ofs] = l2;
        }
        __syncthreads();

        // ---- fragments + MFMA ----
        bf16x8 ah[4], al[4];
        #pragma unroll
        for (int mf = 0; mf < 4; mf++) {
            int r = mf * 16 + frow;
            int ofs = r * 32 + (kf ^ ((r & 3) << 3));
            ah[mf] = *(const bf16x8*)&Ahi[ofs];
            al[mf] = *(const bf16x8*)&Alo[ofs];
        }
        #pragma unroll
        for (int nf = 0; nf < 8; nf++) {
            int rn = w * 128 + nf * 16 + frow;
            int ofs = rn * 32 + (kf ^ ((rn & 3) << 3));
            bf16x8 bh = *(const bf16x8*)&Bhi[ofs];
            bf16x8 bl = *(const bf16x8*)&Blo[ofs];
            #pragma unroll
            for (int mf = 0; mf < 4; mf++) {
                acc[mf][nf] = __builtin_amdgcn_mfma_f32_16x16x32_bf16(ah[mf], bh, acc[mf][nf], 0, 0, 0);
                acc[mf][nf] = __builtin_amdgcn_mfma_f32_16x16x32_bf16(ah[mf], bl, acc[mf][nf], 0, 0, 0);
                acc[mf][nf] = __builtin_amdgcn_mfma_f32_16x16x32_bf16(al[mf], bh, acc[mf][nf], 0, 0, 0);
            }
        }
        __syncthreads();
    }

    // ---- epilogue: bias + f32 store over the packed-x rows ----
    float* outf = (float*)xpk;
    const int rq = (lane >> 4) * 4;
    #pragma unroll
    for (int nf = 0; nf < 8; nf++) {
        int col = w * 128 + nf * 16 + frow;
        float bias = b_ih[col] + b_hh[col];
        #pragma unroll
        for (int mf = 0; mf < 4; mf++) {
            #pragma unroll
            for (int r = 0; r < 4; r++) {
                int row = m0 + mf * 16 + rq + r;
                outf[(size_t)row * HID + col] = acc[mf][nf][r] + bias;
            }
        }
    }
}

// ---------------------------------------------------------------------------
// Kernel B v7 (VERBATIM — replay-proven 2.44 ms): MFMA dot + producer-packed
// bf16 h exchange + full-grid flag barrier.
// ---------------------------------------------------------------------------
__global__ __launch_bounds__(512, 2) void rnn_kernel(
    const float* __restrict__ h0,
    const float* __restrict__ Whh,
    float* __restrict__ out,         // [T][B][H] xp in -> h out; h_last at end
    unsigned* hcomm,                 // [2][B][H] packed bf16 hi/lo exchange
    unsigned* flags)                 // [256*32] zeroed
{
    __shared__ unsigned short Whi[16 * 1024];
    __shared__ unsigned short Wlo[16 * 1024];
    __shared__ unsigned short Hhi[16 * 1024];
    __shared__ unsigned short Hlo[16 * 1024];
    __shared__ f32x4 Pred[8][64];

    const int bid = blockIdx.x;
    const int j0 = (bid & 63) * 16;
    const int b0 = (bid >> 6) * 16;
    const int tid  = threadIdx.x;
    const int lane = tid & 63;
    const int w    = tid >> 6;        // wave 0..7 -> k-range [w*128,(w+1)*128)

    // ---- stage W_hh rows j0..j0+15 as bf16 hi/lo, XOR-swizzled ----
    #pragma unroll
    for (int i = 0; i < 4; i++) {
        int c = i * 512 + tid;            // chunk of 8 elems
        int row = c >> 7;
        int k0 = (c & 127) * 8;
        const float* src = Whh + (size_t)(j0 + row) * HID + k0;
        float4 v0 = *(const float4*)(src);
        float4 v1 = *(const float4*)(src + 4);
        float vv[8] = {v0.x, v0.y, v0.z, v0.w, v1.x, v1.y, v1.z, v1.w};
        bf16x8 hi8, lo8;
        #pragma unroll
        for (int e = 0; e < 8; e++) {
            unsigned short h = f2bf(vv[e]);
            hi8[e] = (short)h;
            lo8[e] = (short)f2bf(vv[e] - bf2f(h));
        }
        int ofs = row * 1024 + (k0 ^ ((row & 7) << 3));
        *(bf16x8*)&Whi[ofs] = hi8;
        *(bf16x8*)&Wlo[ofs] = lo8;
    }

    const int o = tid;                 // tid<256: b = o>>4, j = o&15
    const size_t out_off = (size_t)(b0 + (o >> 4)) * HID + (size_t)(j0 + (o & 15));
    float xp_cur = (tid < 256) ? out[out_off] : 0.f;

    // fragment addressing: lane reads row (lane&15), 8 bf16 at k-base
    const int frow = lane & 15;
    const int ksub = (lane >> 4) * 8;          // 0,8,16,24
    const int sw   = (frow & 7) << 3;

    for (int t = 0; t < T_STEPS; t++) {
        // ---- stage h_{t-1} (16 rows) into Hhi/Hlo ----
        if (t == 0) {
            #pragma unroll
            for (int i = 0; i < 4; i++) {
                int c = i * 512 + tid;
                int row = c >> 7;
                int k0 = (c & 127) * 8;
                const float* p = h0 + (size_t)(b0 + row) * HID + k0;
                float4 v0 = *(const float4*)(p);
                float4 v1 = *(const float4*)(p + 4);
                float vv[8] = {v0.x, v0.y, v0.z, v0.w, v1.x, v1.y, v1.z, v1.w};
                bf16x8 hi8, lo8;
                #pragma unroll
                for (int e = 0; e < 8; e++) {
                    unsigned short h = f2bf(vv[e]);
                    hi8[e] = (short)h;
                    lo8[e] = (short)f2bf(vv[e] - bf2f(h));
                }
                int ofs = row * 1024 + (k0 ^ ((row & 7) << 3));
                *(bf16x8*)&Hhi[ofs] = hi8;
                *(bf16x8*)&Hlo[ofs] = lo8;
            }
        } else {
            const unsigned long long* hsrc64 =
                (const unsigned long long*)(hcomm + (size_t)((t + 1) & 1) * BH_SZ);
            // load-only loop: 16 relaxed-atomic u64 loads, no intervening
            // stores -> issued back-to-back, ONE IF round trip
            unsigned long long pv[16];
            #pragma unroll
            for (int i = 0; i < 4; i++) {
                int c = i * 512 + tid;
                int row = c >> 7;
                int k0 = (c & 127) * 8;
                const unsigned long long* p =
                    hsrc64 + (((size_t)(b0 + row) * HID + k0) >> 1);
                #pragma unroll
                for (int e = 0; e < 4; e++)
                    pv[i * 4 + e] = ld_coh_u64(p + e);
            }
            // unpack + LDS write
            #pragma unroll
            for (int i = 0; i < 4; i++) {
                int c = i * 512 + tid;
                int row = c >> 7;
                int k0 = (c & 127) * 8;
                u32x4 hiu, lou;
                #pragma unroll
                for (int e = 0; e < 4; e++) {
                    unsigned long long q = pv[i * 4 + e];
                    unsigned p0 = (unsigned)q;
                    unsigned p1 = (unsigned)(q >> 32);
                    hiu[e] = (p0 & 0xFFFFu) | (p1 << 16);
                    lou[e] = (p0 >> 16) | (p1 & 0xFFFF0000u);
                }
                int ofs = row * 1024 + (k0 ^ ((row & 7) << 3));
                *(u32x4*)&Hhi[ofs] = hiu;
                *(u32x4*)&Hlo[ofs] = lou;
            }
        }
        __syncthreads();

        // ---- MFMA dot: wave w covers k in [w*128,(w+1)*128) ----
        {
            f32x4 acc = {0.f, 0.f, 0.f, 0.f};
            #pragma unroll
            for (int kk = 0; kk < 4; kk++) {
                int kidx = w * 128 + kk * 32 + ksub;       // full k index
                int ofs  = frow * 1024 + (kidx ^ sw);      // XOR after add
                bf16x8 ahi = *(const bf16x8*)&Hhi[ofs];
                bf16x8 alo = *(const bf16x8*)&Hlo[ofs];
                bf16x8 bhi = *(const bf16x8*)&Whi[ofs];
                bf16x8 blo = *(const bf16x8*)&Wlo[ofs];
                acc = __builtin_amdgcn_mfma_f32_16x16x32_bf16(ahi, bhi, acc, 0, 0, 0);
                acc = __builtin_amdgcn_mfma_f32_16x16x32_bf16(ahi, blo, acc, 0, 0, 0);
                acc = __builtin_amdgcn_mfma_f32_16x16x32_bf16(alo, bhi, acc, 0, 0, 0);
            }
            Pred[w][lane] = acc;   // D: col=lane&15 (j), rows (lane>>4)*4+r (b)
        }
        __syncthreads();

        // ---- reduce + tanh; coherent store ONLY (critical path) ----
        float hn = 0.f;
        if (tid < 256) {
            const int b = o >> 4, j = o & 15;
            const int plane = ((b >> 2) << 4) | j;   // source lane in each wave
            const int pr = b & 3;                    // source reg
            float s = xp_cur;
            #pragma unroll
            for (int k = 0; k < 8; k++) s += Pred[k][plane][pr];
            hn = fast_tanh(s);
            unsigned short hi = f2bf(hn);
            unsigned short lo = f2bf(hn - bf2f(hi));
            unsigned pk = (unsigned)hi | ((unsigned)lo << 16);
            st_coh_u32(hcomm + (size_t)(t & 1) * BH_SZ + out_off, pk);
        }
        __syncthreads();   // drains every thread's coherent h store

        // ---- arrive ----
        if (tid == 0) st_coh_u32(&flags[bid * 32], (unsigned)(t + 1));

        // ---- off-critical-path work overlapping the poll ----
        if (tid < 256) {
            out[(size_t)t * BH_SZ + out_off] = hn;       // cached, own cell
            if (t == T_STEPS - 1)
                out[(size_t)T_STEPS * BH_SZ + out_off] = hn;
        }
        float xp_next = 0.f;
        if (tid < 256 && t + 1 < T_STEPS)
            xp_next = out[(size_t)(t + 1) * BH_SZ + out_off];

        // ---- wait: FULL grid (replay-proven) ----
        if (tid < 64) {
            const unsigned target = (unsigned)(t + 1);
            for (;;) {
                int ok = 1;
                #pragma unroll
                for (int g = 0; g < 4; g++) {
                    unsigned v = ld_coh_u32(&flags[(size_t)(tid + g * 64) * 32]);
                    ok &= (v >= target) ? 1 : 0;
                }
                if (__all(ok)) break;
                __builtin_amdgcn_s_sleep(1);
            }
        }
        __syncthreads();
        xp_cur = xp_next;
    }
}

// ---------------------------------------------------------------------------
extern "C" void kernel_launch(void* const* d_in, const int* in_sizes, int n_in,
                              void* d_out, int out_size, void* d_ws, size_t ws_size,
                              hipStream_t stream)
{
    const float* input  = (const float*)d_in[0];  // [T,B,I]
    const float* hidden = (const float*)d_in[1];  // [B,H]
    const float* W_ih   = (const float*)d_in[2];  // [H,I]
    const float* W_hh   = (const float*)d_in[3];  // [H,H]
    const float* b_ih   = (const float*)d_in[4];  // [H]
    const float* b_hh   = (const float*)d_in[5];  // [H]
    float* out = (float*)d_out;

    // ws layout: flags 32 KB @0 | hcomm 512 KB @32K | Wpk 4 MB @1M
    unsigned* flags = (unsigned*)d_ws;
    unsigned* hcomm = (unsigned*)((char*)d_ws + 256 * 32 * sizeof(unsigned));
    unsigned* Wpk   = (unsigned*)((char*)d_ws + (size_t)1 * 1024 * 1024);

    hipMemsetAsync(flags, 0, 256 * 32 * sizeof(unsigned), stream);

    // pack x in-place into d_out (u32 view), W_ih into ws
    const int n4x = (T_STEPS * BATCH * IN_DIM) / 4;
    const int n4w = (HID * IN_DIM) / 4;
    pack_bf16_kernel<<<2048, 256, 0, stream>>>(input, (unsigned*)out, n4x);
    pack_bf16_kernel<<<1024, 256, 0, stream>>>(W_ih, Wpk, n4w);

    // xp = x @ W_ih^T + bias  (in-place over the packed x)
    xproj_mfma_kernel<<<(T_STEPS * BATCH) / 64, 512, 0, stream>>>(
        (unsigned*)out, Wpk, b_ih, b_hh);

    rnn_kernel<<<256, 512, 0, stream>>>(hidden, W_hh, out, hcomm, flags);
}

// Round 10
// 2440.114 us; speedup vs baseline: 3.1363x; 1.1613x over previous
//
#include <hip/hip_runtime.h>
#include <hip/hip_bf16.h>
#include <math.h>

#define T_STEPS 512
#define BATCH   64
#define IN_DIM  1024
#define HID     1024
#define BH_SZ   (BATCH * HID)

typedef short bf16x8 __attribute__((ext_vector_type(8)));
typedef float f32x4  __attribute__((ext_vector_type(4)));
typedef unsigned u32x4 __attribute__((ext_vector_type(4)));
typedef unsigned long long u64;

// ---- coherent (agent-scope, cache-bypassing) accessors --------------------
__device__ __forceinline__ unsigned ld_coh_u32(const unsigned* p) {
    return __hip_atomic_load(p, __ATOMIC_RELAXED, __HIP_MEMORY_SCOPE_AGENT);
}
__device__ __forceinline__ void st_coh_u32(unsigned* p, unsigned v) {
    __hip_atomic_store(p, v, __ATOMIC_RELAXED, __HIP_MEMORY_SCOPE_AGENT);
}
__device__ __forceinline__ u64 ld_coh_u64(const u64* p) {
    return __hip_atomic_load(p, __ATOMIC_RELAXED, __HIP_MEMORY_SCOPE_AGENT);
}

// ---- bf16 split helpers (RNE) ---------------------------------------------
__device__ __forceinline__ unsigned short f2bf(float x) {
    unsigned u = __builtin_bit_cast(unsigned, x);
    unsigned r = u + 0x7FFFu + ((u >> 16) & 1u);
    return (unsigned short)(r >> 16);
}
__device__ __forceinline__ float bf2f(unsigned short h) {
    unsigned u = ((unsigned)h) << 16;
    return __builtin_bit_cast(float, u);
}
__device__ __forceinline__ float fast_tanh(float x) {
    float e = __expf(2.0f * x);
    return 1.0f - 2.0f * __builtin_amdgcn_rcpf(e + 1.0f);
}

// ---------------------------------------------------------------------------
// Fused RNN kernel v10: xproj folded into the recurrence's idle (poll) window.
//  - per step, MFMA phase computes W_hh·h (3-term split, W_hh frags in REGS)
//    PLUS x_t·W_ih^T (1-term bf16) from LDS-staged x_t
//  - x_{t+1} is a pure input -> prefetched + converted + LDS-staged during the
//    barrier poll window (previously dead time)
//  - h exchange + full-grid flag barrier: BYTE-IDENTICAL to replay-proven v7
// LDS: Wih(hi) 32K + Hhi 32K + Hlo 32K + Xh 32K + Pred 8K = 136 KB.
// ---------------------------------------------------------------------------
__global__ __launch_bounds__(512, 1) void rnn_fused_kernel(
    const float* __restrict__ x,      // [T][B][I] raw input
    const float* __restrict__ h0,     // [B][H]
    const float* __restrict__ W_ih,   // [H][I]
    const float* __restrict__ Whh,    // [H][H]
    const float* __restrict__ b_ih,   // [H]
    const float* __restrict__ b_hh,   // [H]
    float* __restrict__ out,          // [T][B][H] h out; h_last at end
    unsigned* hcomm,                  // [2][B][H] packed bf16 hi/lo exchange
    unsigned* flags)                  // [256*32] zeroed
{
    __shared__ unsigned short Wih[16 * 1024];   // W_ih rows j0.., bf16 hi only
    __shared__ unsigned short Hhi[16 * 1024];
    __shared__ unsigned short Hlo[16 * 1024];
    __shared__ unsigned short Xh [16 * 1024];   // x_t rows b0.., bf16
    __shared__ f32x4 Pred[8][64];

    const int bid = blockIdx.x;
    const int j0 = (bid & 63) * 16;
    const int b0 = (bid >> 6) * 16;
    const int tid  = threadIdx.x;
    const int lane = tid & 63;
    const int w    = tid >> 6;        // wave 0..7 -> k-range [w*128,(w+1)*128)

    // fragment addressing: lane reads row (lane&15), 8 bf16 at k-base
    const int frow = lane & 15;
    const int ksub = (lane >> 4) * 8;          // 0,8,16,24
    const int sw   = (frow & 7) << 3;

    // ---- prologue 1: stage W_ih rows j0..j0+15 (bf16 hi), XOR-swizzled ----
    #pragma unroll
    for (int i = 0; i < 4; i++) {
        int c = i * 512 + tid;
        int row = c >> 7;
        int k0 = (c & 127) * 8;
        const float* src = W_ih + (size_t)(j0 + row) * IN_DIM + k0;
        float4 v0 = *(const float4*)(src);
        float4 v1 = *(const float4*)(src + 4);
        float vv[8] = {v0.x, v0.y, v0.z, v0.w, v1.x, v1.y, v1.z, v1.w};
        bf16x8 hi8;
        #pragma unroll
        for (int e = 0; e < 8; e++) hi8[e] = (short)f2bf(vv[e]);
        int ofs = row * 1024 + (k0 ^ ((row & 7) << 3));
        *(bf16x8*)&Wih[ofs] = hi8;
    }

    // ---- prologue 2: stage W_hh split into Hhi/Hlo (TEMP), read frags ----
    #pragma unroll
    for (int i = 0; i < 4; i++) {
        int c = i * 512 + tid;
        int row = c >> 7;
        int k0 = (c & 127) * 8;
        const float* src = Whh + (size_t)(j0 + row) * HID + k0;
        float4 v0 = *(const float4*)(src);
        float4 v1 = *(const float4*)(src + 4);
        float vv[8] = {v0.x, v0.y, v0.z, v0.w, v1.x, v1.y, v1.z, v1.w};
        bf16x8 hi8, lo8;
        #pragma unroll
        for (int e = 0; e < 8; e++) {
            unsigned short h = f2bf(vv[e]);
            hi8[e] = (short)h;
            lo8[e] = (short)f2bf(vv[e] - bf2f(h));
        }
        int ofs = row * 1024 + (k0 ^ ((row & 7) << 3));
        *(bf16x8*)&Hhi[ofs] = hi8;
        *(bf16x8*)&Hlo[ofs] = lo8;
    }
    __syncthreads();
    bf16x8 wh[4], wl[4];                       // W_hh frags in registers
    #pragma unroll
    for (int kk = 0; kk < 4; kk++) {
        int kidx = w * 128 + kk * 32 + ksub;
        int ofs  = frow * 1024 + (kidx ^ sw);
        wh[kk] = *(const bf16x8*)&Hhi[ofs];
        wl[kk] = *(const bf16x8*)&Hlo[ofs];
    }
    __syncthreads();   // frags read -> Hhi/Hlo reusable for h staging

    // ---- prologue 3: stage x_0 into Xh ----
    #pragma unroll
    for (int i = 0; i < 4; i++) {
        int c = i * 512 + tid;
        int row = c >> 7;
        int k0 = (c & 127) * 8;
        const float* p = x + (size_t)(b0 + row) * IN_DIM + k0;   // t = 0
        float4 v0 = *(const float4*)(p);
        float4 v1 = *(const float4*)(p + 4);
        float vv[8] = {v0.x, v0.y, v0.z, v0.w, v1.x, v1.y, v1.z, v1.w};
        bf16x8 hi8;
        #pragma unroll
        for (int e = 0; e < 8; e++) hi8[e] = (short)f2bf(vv[e]);
        int ofs = row * 1024 + (k0 ^ ((row & 7) << 3));
        *(bf16x8*)&Xh[ofs] = hi8;
    }

    const int o = tid;                 // tid<256: b = o>>4, j = o&15
    const size_t out_off = (size_t)(b0 + (o >> 4)) * HID + (size_t)(j0 + (o & 15));
    float bias = 0.f;
    if (tid < 256) bias = b_ih[j0 + (o & 15)] + b_hh[j0 + (o & 15)];

    for (int t = 0; t < T_STEPS; t++) {
        // ---- stage h_{t-1} (16 rows) into Hhi/Hlo (v7 verbatim) ----
        if (t == 0) {
            #pragma unroll
            for (int i = 0; i < 4; i++) {
                int c = i * 512 + tid;
                int row = c >> 7;
                int k0 = (c & 127) * 8;
                const float* p = h0 + (size_t)(b0 + row) * HID + k0;
                float4 v0 = *(const float4*)(p);
                float4 v1 = *(const float4*)(p + 4);
                float vv[8] = {v0.x, v0.y, v0.z, v0.w, v1.x, v1.y, v1.z, v1.w};
                bf16x8 hi8, lo8;
                #pragma unroll
                for (int e = 0; e < 8; e++) {
                    unsigned short h = f2bf(vv[e]);
                    hi8[e] = (short)h;
                    lo8[e] = (short)f2bf(vv[e] - bf2f(h));
                }
                int ofs = row * 1024 + (k0 ^ ((row & 7) << 3));
                *(bf16x8*)&Hhi[ofs] = hi8;
                *(bf16x8*)&Hlo[ofs] = lo8;
            }
        } else {
            const u64* hsrc64 = (const u64*)(hcomm + (size_t)((t + 1) & 1) * BH_SZ);
            u64 pv[16];
            #pragma unroll
            for (int i = 0; i < 4; i++) {
                int c = i * 512 + tid;
                int row = c >> 7;
                int k0 = (c & 127) * 8;
                const u64* p = hsrc64 + (((size_t)(b0 + row) * HID + k0) >> 1);
                #pragma unroll
                for (int e = 0; e < 4; e++)
                    pv[i * 4 + e] = ld_coh_u64(p + e);
            }
            #pragma unroll
            for (int i = 0; i < 4; i++) {
                int c = i * 512 + tid;
                int row = c >> 7;
                int k0 = (c & 127) * 8;
                u32x4 hiu, lou;
                #pragma unroll
                for (int e = 0; e < 4; e++) {
                    u64 q = pv[i * 4 + e];
                    unsigned p0 = (unsigned)q;
                    unsigned p1 = (unsigned)(q >> 32);
                    hiu[e] = (p0 & 0xFFFFu) | (p1 << 16);
                    lou[e] = (p0 >> 16) | (p1 & 0xFFFF0000u);
                }
                int ofs = row * 1024 + (k0 ^ ((row & 7) << 3));
                *(u32x4*)&Hhi[ofs] = hiu;
                *(u32x4*)&Hlo[ofs] = lou;
            }
        }
        __syncthreads();   // sync A

        // ---- MFMA: W_hh·h (3-term, reg frags) + W_ih·x_t (1-term) ----
        {
            f32x4 acc = {0.f, 0.f, 0.f, 0.f};
            #pragma unroll
            for (int kk = 0; kk < 4; kk++) {
                int kidx = w * 128 + kk * 32 + ksub;
                int ofs  = frow * 1024 + (kidx ^ sw);
                bf16x8 ahi = *(const bf16x8*)&Hhi[ofs];
                bf16x8 alo = *(const bf16x8*)&Hlo[ofs];
                bf16x8 xh  = *(const bf16x8*)&Xh[ofs];
                bf16x8 wi  = *(const bf16x8*)&Wih[ofs];
                acc = __builtin_amdgcn_mfma_f32_16x16x32_bf16(ahi, wh[kk], acc, 0, 0, 0);
                acc = __builtin_amdgcn_mfma_f32_16x16x32_bf16(ahi, wl[kk], acc, 0, 0, 0);
                acc = __builtin_amdgcn_mfma_f32_16x16x32_bf16(alo, wh[kk], acc, 0, 0, 0);
                acc = __builtin_amdgcn_mfma_f32_16x16x32_bf16(xh,  wi,     acc, 0, 0, 0);
            }
            Pred[w][lane] = acc;
        }
        __syncthreads();   // sync B

        // ---- reduce + bias + tanh; coherent store (critical path) ----
        float hn = 0.f;
        if (tid < 256) {
            const int b = o >> 4, j = o & 15;
            const int plane = ((b >> 2) << 4) | j;
            const int pr = b & 3;
            float s = bias;
            #pragma unroll
            for (int k = 0; k < 8; k++) s += Pred[k][plane][pr];
            hn = fast_tanh(s);
            unsigned short hi = f2bf(hn);
            unsigned short lo = f2bf(hn - bf2f(hi));
            unsigned pk = (unsigned)hi | ((unsigned)lo << 16);
            st_coh_u32(hcomm + (size_t)(t & 1) * BH_SZ + out_off, pk);
        }
        __syncthreads();   // sync C: drains every thread's coherent h store

        // ---- arrive ----
        if (tid == 0) st_coh_u32(&flags[bid * 32], (unsigned)(t + 1));

        // ---- bubble work: out stores + x_{t+1} prefetch into Xh ----
        if (tid < 256) {
            out[(size_t)t * BH_SZ + out_off] = hn;
            if (t == T_STEPS - 1)
                out[(size_t)T_STEPS * BH_SZ + out_off] = hn;
        }
        if (t + 1 < T_STEPS) {
            const float* xs = x + (size_t)(t + 1) * BH_SZ;   // B*I == BH_SZ
            #pragma unroll
            for (int i = 0; i < 4; i++) {
                int c = i * 512 + tid;
                int row = c >> 7;
                int k0 = (c & 127) * 8;
                const float* p = xs + (size_t)(b0 + row) * IN_DIM + k0;
                float4 v0 = *(const float4*)(p);
                float4 v1 = *(const float4*)(p + 4);
                float vv[8] = {v0.x, v0.y, v0.z, v0.w, v1.x, v1.y, v1.z, v1.w};
                bf16x8 hi8;
                #pragma unroll
                for (int e = 0; e < 8; e++) hi8[e] = (short)f2bf(vv[e]);
                int ofs = row * 1024 + (k0 ^ ((row & 7) << 3));
                *(bf16x8*)&Xh[ofs] = hi8;   // Xh reads done at sync B
            }
        }

        // ---- wait: FULL grid (replay-proven v7 skeleton) ----
        if (tid < 64) {
            const unsigned target = (unsigned)(t + 1);
            for (;;) {
                int ok = 1;
                #pragma unroll
                for (int g = 0; g < 4; g++) {
                    unsigned v = ld_coh_u32(&flags[(size_t)(tid + g * 64) * 32]);
                    ok &= (v >= target) ? 1 : 0;
                }
                if (__all(ok)) break;
                __builtin_amdgcn_s_sleep(1);
            }
        }
        __syncthreads();   // sync D
    }
}

// ---------------------------------------------------------------------------
extern "C" void kernel_launch(void* const* d_in, const int* in_sizes, int n_in,
                              void* d_out, int out_size, void* d_ws, size_t ws_size,
                              hipStream_t stream)
{
    const float* input  = (const float*)d_in[0];  // [T,B,I]
    const float* hidden = (const float*)d_in[1];  // [B,H]
    const float* W_ih   = (const float*)d_in[2];  // [H,I]
    const float* W_hh   = (const float*)d_in[3];  // [H,H]
    const float* b_ih   = (const float*)d_in[4];  // [H]
    const float* b_hh   = (const float*)d_in[5];  // [H]
    float* out = (float*)d_out;

    unsigned* flags = (unsigned*)d_ws;                          // 32 KB
    unsigned* hcomm = (unsigned*)((char*)d_ws + 256 * 32 * sizeof(unsigned));
    hipMemsetAsync(flags, 0, 256 * 32 * sizeof(unsigned), stream);

    rnn_fused_kernel<<<256, 512, 0, stream>>>(
        input, hidden, W_ih, W_hh, b_ih, b_hh, out, hcomm, flags);
}